// Round 2
// baseline (458.976 us; speedup 1.0000x reference)
//
#include <hip/hip_runtime.h>
#include <math.h>

// TreeAttention: N=16, T=S=2048, H=64, KS=64, INIT_W=16, 7 tree iterations.
// One wave (64 lanes) per (n,t) row. 4 waves per block.

constexpr int Tn = 2048;
constexpr int Hn = 64;
constexpr int WV = 4;                 // waves per block
constexpr float NEGF = -1e9f;

// monotonic float -> uint mapping (no NaNs expected)
__device__ __forceinline__ unsigned int ord32(float f) {
    unsigned int u = __float_as_uint(f);
    return (u & 0x80000000u) ? ~u : (u | 0x80000000u);
}

// sort key: primary score descending, secondary index ascending (stable top_k)
__device__ __forceinline__ unsigned long long packkey(float s, int e) {
    return ((unsigned long long)ord32(s) << 32) |
           (unsigned long long)(unsigned int)(~e);
}

// pos = clip(round_half_even(z * ratio), 0, Tn-1); ratio = (t+1)/w2 (exact fp32)
__device__ __forceinline__ int cpos(int z, float ratio) {
    float x = (float)z * ratio;          // exact: z*(t+1) < 2^23
    int p = (int)rintf(x);               // v_rndne_f32 = half-to-even
    p = p < 0 ? 0 : p;
    p = p > (Tn - 1) ? (Tn - 1) : p;
    return p;
}

// deterministic sequential dot(q, keyrow) over H=64 (same order everywhere ->
// equal positions give bit-identical scores, preserving reference tie-breaks)
__device__ __forceinline__ float dotq(const float* __restrict__ krow,
                                      const float* qs) {
    float acc = 0.f;
#pragma unroll
    for (int h = 0; h < Hn; h += 4) {
        float4 kv = *reinterpret_cast<const float4*>(krow + h);
        float4 qv = *reinterpret_cast<const float4*>(qs + h);
        acc = fmaf(qv.x, kv.x, acc);
        acc = fmaf(qv.y, kv.y, acc);
        acc = fmaf(qv.z, kv.z, acc);
        acc = fmaf(qv.w, kv.w, acc);
    }
    return acc;
}

__global__ void TreeAttention_70257075028607_kernel(
        const float* __restrict__ Q, const float* __restrict__ Kk,
        const float* __restrict__ V, float* __restrict__ O) {
    __shared__ __align__(16) float              qsh[WV][Hn];
    __shared__ __align__(16) unsigned long long keysh[WV][128];
    __shared__ __align__(16) float              esch[WV][128];
    __shared__ __align__(16) int                ezh[WV][128];
    __shared__ __align__(16) float              nsch[WV][64];
    __shared__ __align__(16) int                nzh[WV][64];

    const int lane = threadIdx.x & 63;
    const int wv   = threadIdx.x >> 6;
    const int row  = blockIdx.x * WV + wv;          // n*T + t
    const int n    = row >> 11;
    const int t    = row & (Tn - 1);
    const float tp1 = (float)(t + 1);               // tsrc (exact)

    const float* qrow = Q + (size_t)row * Hn;
    const float* Kb   = Kk + (size_t)n * Tn * Hn;
    const float* Vb   = V  + (size_t)n * Tn * Hn;

    float* qs = qsh[wv];
    unsigned long long* kz = keysh[wv];
    float* es = esch[wv];
    int*   ez = ezh[wv];
    float* ns = nsch[wv];
    int*   nz = nzh[wv];

    qs[lane] = qrow[lane];
    __syncthreads();

    int   myz  = 0;
    float mysc = NEGF;

    // ---- iteration 1: w2=32, 32 candidates, element index == z ----
    {
        const float ratio = tp1 * (1.0f / 32.0f);
        if (lane < 32) {
            float s = dotq(Kb + (size_t)cpos(lane, ratio) * Hn, qs);
            es[lane] = s;
            kz[lane] = packkey(s, lane);
        }
        __syncthreads();
        if (lane < 32) {
            unsigned long long mk = kz[lane];
            int r = 0;
#pragma unroll 8
            for (int j = 0; j < 32; ++j) r += (kz[j] > mk) ? 1 : 0;
            ns[r] = es[lane];
            nz[r] = lane;
        }
        __syncthreads();
        if (lane < 32) { myz = nz[lane]; mysc = ns[lane]; }
        __syncthreads();
    }

    // ---- iteration 2: w2=64, 32 parents -> 64 elements, keep all (sorted) ----
    {
        const float ratio = tp1 * (1.0f / 64.0f);
        if (lane < 32) {
            int z1 = 2 * myz + 1;
            float s1 = dotq(Kb + (size_t)cpos(z1, ratio) * Hn, qs);
            int e0 = 2 * lane;
            ez[e0]     = 2 * myz; es[e0]     = mysc; kz[e0]     = packkey(mysc, e0);
            ez[e0 + 1] = z1;      es[e0 + 1] = s1;   kz[e0 + 1] = packkey(s1, e0 + 1);
        }
        __syncthreads();
        {
            unsigned long long mk = kz[lane];
            int r = 0;
#pragma unroll 8
            for (int j = 0; j < 64; ++j) r += (kz[j] > mk) ? 1 : 0;
            ns[r] = es[lane];
            nz[r] = ez[lane];
        }
        __syncthreads();
        myz = nz[lane];
        mysc = ns[lane];
        __syncthreads();
    }

    // ---- iterations 3..7: w2=128..2048, 64 parents -> 128 elements, keep 64 ----
#pragma unroll
    for (int it = 0; it < 5; ++it) {
        const float ratio = tp1 * ldexpf(1.0f, -(7 + it));
        int z1 = 2 * myz + 1;
        float s1 = dotq(Kb + (size_t)cpos(z1, ratio) * Hn, qs);
        int e0 = 2 * lane;
        ez[e0]     = 2 * myz; es[e0]     = mysc; kz[e0]     = packkey(mysc, e0);
        ez[e0 + 1] = z1;      es[e0 + 1] = s1;   kz[e0 + 1] = packkey(s1, e0 + 1);
        __syncthreads();
        unsigned long long k0 = kz[lane];
        unsigned long long k1 = kz[lane + 64];
        int r0 = 0, r1 = 0;
        const ulonglong2* kp = reinterpret_cast<const ulonglong2*>(kz);
#pragma unroll 4
        for (int j = 0; j < 64; ++j) {
            ulonglong2 kj = kp[j];
            r0 += (kj.x > k0) ? 1 : 0;
            r0 += (kj.y > k0) ? 1 : 0;
            r1 += (kj.x > k1) ? 1 : 0;
            r1 += (kj.y > k1) ? 1 : 0;
        }
        if (r0 < 64) { ns[r0] = es[lane];      nz[r0] = ez[lane]; }
        if (r1 < 64) { ns[r1] = es[lane + 64]; nz[r1] = ez[lane + 64]; }
        __syncthreads();
        myz = nz[lane];
        mysc = ns[lane];
        __syncthreads();
    }

    // ---- final: pos at w=2048, causal mask, softmax, PV ----
    {
        const float ratio = tp1 * (1.0f / 2048.0f);
        int  mypos = cpos(myz, ratio);
        bool valid = ((float)mypos < tp1);           // pos < tsrc
        float s = valid ? mysc * 0.125f : NEGF;      // / sqrt(64)

        float m = s;
#pragma unroll
        for (int off = 32; off >= 1; off >>= 1)
            m = fmaxf(m, __shfl_xor(m, off, 64));
        float p = expf(s - m);
        float sum = p;
#pragma unroll
        for (int off = 32; off >= 1; off >>= 1)
            sum += __shfl_xor(sum, off, 64);
        p = p / sum;
        if (!valid) p = 0.f;

        ns[lane] = p;        // reuse buffers: p
        nz[lane] = mypos;    // pos
        __syncthreads();

        float acc = 0.f;
#pragma unroll 8
        for (int j = 0; j < 64; ++j) {
            acc = fmaf(ns[j], Vb[(size_t)nz[j] * Hn + lane], acc);
        }
        O[(size_t)row * Hn + lane] = acc;
    }
}

extern "C" void kernel_launch(void* const* d_in, const int* in_sizes, int n_in,
                              void* d_out, int out_size, void* d_ws, size_t ws_size,
                              hipStream_t stream) {
    const float* Q = (const float*)d_in[0];
    const float* K = (const float*)d_in[1];
    const float* V = (const float*)d_in[2];
    float* O = (float*)d_out;

    const int rows = in_sizes[0] / Hn;        // N*T = 32768
    const int blocks = rows / WV;             // 8192
    TreeAttention_70257075028607_kernel<<<blocks, WV * 64, 0, stream>>>(Q, K, V, O);
}

// Round 9
// 439.902 us; speedup vs baseline: 1.0434x; 1.0434x over previous
//
#include <hip/hip_runtime.h>
#include <math.h>

// TreeAttention: N=16, T=S=2048, H=64, KS=64, INIT_W=16, 7 tree iterations.
// One wave per (n,t) row; 4 waves/block; wave-private LDS, no __syncthreads.
// Scoring uses the round-2 sequential-fma dot (bit-exact selection order);
// ranking uses shfl-bitonic sort + binary-search merge on packed u64 keys.

constexpr int Tn = 2048;
constexpr int Hn = 64;
constexpr int WV = 4;
constexpr float NEGF = -1e9f;

typedef unsigned long long u64;
typedef unsigned int u32;

// wave-local LDS ordering: drain LDS ops + stop compiler reordering
#define WWAIT() asm volatile("s_waitcnt lgkmcnt(0)" ::: "memory")

__device__ __forceinline__ u32 ord32(float f) {
    u32 u = __float_as_uint(f);
    return (u & 0x80000000u) ? ~u : (u | 0x80000000u);
}
// total order: score desc, element index asc  (== jax.lax.top_k stable order)
__device__ __forceinline__ u64 packkey(float s, int e) {
    return ((u64)ord32(s) << 32) | (u64)(u32)(~e);
}
__device__ __forceinline__ float dec_score(u64 k) {
    u32 o = (u32)(k >> 32);
    u32 u = (o & 0x80000000u) ? (o & 0x7fffffffu) : ~o;
    return __uint_as_float(u);
}
__device__ __forceinline__ int dec_e(u64 k) { return (int)(~(u32)k); }

// pos = clip(round_half_even(z * ratio), 0, Tn-1); ratio=(t+1)/w2 exact fp32
__device__ __forceinline__ int cpos(int z, float ratio) {
    float x = (float)z * ratio;          // exact: z*(t+1) < 2^23
    int p = (int)rintf(x);               // v_rndne_f32 = half-to-even
    p = p < 0 ? 0 : p;
    p = p > (Tn - 1) ? (Tn - 1) : p;
    return p;
}

// round-2 sequential-fma dot: ONE chain in element order 0..63. This exact
// order is what makes equal-pos scores bit-identical AND matches the
// reference's selections within tolerance (empirical: absmax 3.9e-3).
__device__ __forceinline__ float dotq(const float* __restrict__ krow,
                                      const float* qs) {
    float acc = 0.f;
#pragma unroll
    for (int h = 0; h < Hn; h += 4) {
        float4 kv = *reinterpret_cast<const float4*>(krow + h);
        float4 qv = *reinterpret_cast<const float4*>(qs + h);
        acc = fmaf(qv.x, kv.x, acc);
        acc = fmaf(qv.y, kv.y, acc);
        acc = fmaf(qv.z, kv.z, acc);
        acc = fmaf(qv.w, kv.w, acc);
    }
    return acc;
}

__device__ __forceinline__ u64 shflx64(u64 v, int m) {
    u32 lo = (u32)__shfl_xor((int)(u32)v, m, 64);
    u32 hi = (u32)__shfl_xor((int)(v >> 32), m, 64);
    return ((u64)hi << 32) | lo;
}

// descending bitonic sort of one u64 key per lane over lanes 0..N-1
// (N=32: upper-half lanes sort their own inert filler, never cross j<=16)
template<int N>
__device__ __forceinline__ u64 bitonic_desc(u64 key, int lane) {
#pragma unroll
    for (int k = 2; k <= N; k <<= 1) {
#pragma unroll
        for (int j = k >> 1; j >= 1; j >>= 1) {
            u64 pk = shflx64(key, j);
            bool wmax = (((lane & j) == 0) == ((lane & k) == 0));
            key = ((key > pk) == wmax) ? key : pk;
        }
    }
    return key;
}

// count of elements > x in descending-sorted LDS list D[0..N)
template<int N>
__device__ __forceinline__ int cnt_gt(const u64* D, u64 x) {
    int c = 0;
#pragma unroll
    for (int s = N; s >= 1; s >>= 1) {
        if (c + s <= N && D[c + s - 1] > x) c += s;
    }
    return c;
}

__global__ void __launch_bounds__(256)
TreeAttention_70257075028607_kernel(
        const float* __restrict__ Q, const float* __restrict__ Kk,
        const float* __restrict__ V, float* __restrict__ O) {
    __shared__ __align__(16) float qsh[WV][Hn];
    __shared__ __align__(16) u64   Lsh[WV][64];
    __shared__ __align__(16) u64   Rsh[WV][64];
    __shared__ __align__(16) u64   Osh[WV][64];

    const int lane = threadIdx.x & 63;
    const int wv   = threadIdx.x >> 6;
    const int row  = blockIdx.x * WV + wv;      // n*T + t
    const int n    = row >> 11;
    const int t    = row & (Tn - 1);
    const float tp1 = (float)(t + 1);

    const float* qrow = Q + (size_t)row * Hn;
    const float* Kb   = Kk + (size_t)n * Tn * Hn;
    const float* Vb   = V  + (size_t)n * Tn * Hn;

    float* qs = qsh[wv];
    u64* Lb = Lsh[wv];
    u64* Rb = Rsh[wv];
    u64* Ob = Osh[wv];

    qs[lane] = qrow[lane];
    WWAIT();

    int   myz  = 0;
    float mysc = NEGF;

    // ---- iter 1: w2=32, cells z=0..31: score + register bitonic sort ----
    {
        const float ratio = tp1 * (1.f / 32.f);
        u64 key;
        if (lane < 32) {
            float s = dotq(Kb + (size_t)cpos(lane, ratio) * Hn, qs);
            key = packkey(s, lane);
        } else {
            key = (u64)lane;                     // inert filler, never crosses
        }
        key = bitonic_desc<32>(key, lane);
        if (lane < 32) { myz = dec_e(key); mysc = dec_score(key); }
    }

    // ---- iter 2: w2=64, 32 parents -> 64 children, keep all (sorted) ----
    {
        const float ratio = tp1 * (1.f / 64.f);
        u64 Lk = packkey(mysc, 2 * lane);        // parents sorted => L sorted
        u64 Rs;
        if (lane < 32) {
            float s1 = dotq(Kb + (size_t)cpos(2 * myz + 1, ratio) * Hn, qs);
            Rs = packkey(s1, 2 * lane + 1);
        } else {
            Rs = (u64)lane;
        }
        Rs = bitonic_desc<32>(Rs, lane);
        if (lane < 32) { Lb[lane] = Lk; Rb[lane] = Rs; }
        WWAIT();
        if (lane < 32) {
            int rL = lane + cnt_gt<32>(Rb, Lk);  // merge ranks: perm of 0..63
            int rR = lane + cnt_gt<32>(Lb, Rs);
            Ob[rL] = Lk;
            Ob[rR] = Rs;
        }
        WWAIT();
        u64 kk = Ob[lane];
        int e  = dec_e(kk);
        int pz = __shfl(myz, e >> 1, 64);
        myz  = 2 * pz + (e & 1);
        mysc = dec_score(kk);
    }

    // ---- iters 3..7: 64 parents -> 128 children, keep top-64 sorted ----
#pragma unroll
    for (int it = 0; it < 5; ++it) {
        const float ratio = tp1 * ldexpf(1.0f, -(7 + it));
        float s1 = dotq(Kb + (size_t)cpos(2 * myz + 1, ratio) * Hn, qs);
        u64 Lk = packkey(mysc, 2 * lane);        // sorted: parents in rank order
        u64 Rs = bitonic_desc<64>(packkey(s1, 2 * lane + 1), lane);
        Lb[lane] = Lk;
        Rb[lane] = Rs;
        WWAIT();
        int rL = lane + cnt_gt<64>(Rb, Lk);      // ranks: perm of 0..127
        int rR = lane + cnt_gt<64>(Lb, Rs);
        if (rL < 64) Ob[rL] = Lk;
        if (rR < 64) Ob[rR] = Rs;
        WWAIT();
        u64 kk = Ob[lane];
        int e  = dec_e(kk);
        int pz = __shfl(myz, e >> 1, 64);
        myz  = 2 * pz + (e & 1);
        mysc = dec_score(kk);
    }

    // ---- final: causal mask, softmax over 64, PV gather ----
    {
        int mypos  = cpos(myz, tp1 * (1.f / 2048.f));
        bool valid = ((float)mypos < tp1);
        float s = valid ? mysc * 0.125f : NEGF;  // / sqrt(64)

        float m = s;
#pragma unroll
        for (int off = 32; off >= 1; off >>= 1)
            m = fmaxf(m, __shfl_xor(m, off, 64));
        float p = expf(s - m);
        float sum = p;
#pragma unroll
        for (int off = 32; off >= 1; off >>= 1)
            sum += __shfl_xor(sum, off, 64);
        p = p / sum;
        if (!valid) p = 0.f;

        Ob[lane] = ((u64)(u32)mypos << 32) | __float_as_uint(p);
        WWAIT();

        float acc = 0.f;
#pragma unroll 8
        for (int jj = 0; jj < 64; ++jj) {
            u64 w = Ob[jj];
            acc = fmaf(__uint_as_float((u32)w),
                       Vb[(size_t)(w >> 32) * Hn + lane], acc);
        }
        O[(size_t)row * Hn + lane] = acc;
    }
}

extern "C" void kernel_launch(void* const* d_in, const int* in_sizes, int n_in,
                              void* d_out, int out_size, void* d_ws, size_t ws_size,
                              hipStream_t stream) {
    const float* Q = (const float*)d_in[0];
    const float* K = (const float*)d_in[1];
    const float* V = (const float*)d_in[2];
    float* O = (float*)d_out;

    const int rows = in_sizes[0] / Hn;   // N*T = 32768
    const int blocks = rows / WV;        // 8192
    TreeAttention_70257075028607_kernel<<<blocks, WV * 64, 0, stream>>>(Q, K, V, O);
}

// Round 11
// 406.821 us; speedup vs baseline: 1.1282x; 1.0813x over previous
//
#include <hip/hip_runtime.h>
#include <math.h>

// TreeAttention: N=16, T=S=2048, H=64, KS=64, INIT_W=16, 7 tree iterations.
// One wave per (n,t) row; 4 waves/block; wave-private LDS, no __syncthreads.
// K rows are DMA-staged to LDS (global_load_lds, 16 lines/instr vs 64 for
// lane-per-row) and dotted with the SAME sequential fmaf chain (order 0..63)
// as the passing round-9 kernel -> bit-identical scores and selections.

constexpr int Tn = 2048;
constexpr int Hn = 64;
constexpr int WV = 4;
constexpr float NEGF = -1e9f;

typedef unsigned long long u64;
typedef unsigned int u32;

// wave-local LDS ordering: drain LDS ops + stop compiler reordering
#define WWAIT() asm volatile("s_waitcnt lgkmcnt(0)" ::: "memory")
#define VMW(n)  asm volatile("s_waitcnt vmcnt(" #n ")" ::: "memory")

__device__ __forceinline__ u32 ord32(float f) {
    u32 u = __float_as_uint(f);
    return (u & 0x80000000u) ? ~u : (u | 0x80000000u);
}
// total order: score desc, element index asc  (== jax.lax.top_k stable order)
__device__ __forceinline__ u64 packkey(float s, int e) {
    return ((u64)ord32(s) << 32) | (u64)(u32)(~e);
}
__device__ __forceinline__ float dec_score(u64 k) {
    u32 o = (u32)(k >> 32);
    u32 u = (o & 0x80000000u) ? (o & 0x7fffffffu) : ~o;
    return __uint_as_float(u);
}
__device__ __forceinline__ int dec_e(u64 k) { return (int)(~(u32)k); }

// pos = clip(round_half_even(z * ratio), 0, Tn-1); ratio=(t+1)/w2 exact fp32
__device__ __forceinline__ int cpos(int z, float ratio) {
    float x = (float)z * ratio;          // exact: z*(t+1) < 2^23
    int p = (int)rintf(x);               // v_rndne_f32 = half-to-even
    p = p < 0 ? 0 : p;
    p = p > (Tn - 1) ? (Tn - 1) : p;
    return p;
}

__device__ __forceinline__ u64 shflx64(u64 v, int m) {
    u32 lo = (u32)__shfl_xor((int)(u32)v, m, 64);
    u32 hi = (u32)__shfl_xor((int)(v >> 32), m, 64);
    return ((u64)hi << 32) | lo;
}

// descending bitonic sort of one u64 key per lane over lanes 0..N-1
template<int N>
__device__ __forceinline__ u64 bitonic_desc(u64 key, int lane) {
#pragma unroll
    for (int k = 2; k <= N; k <<= 1) {
#pragma unroll
        for (int j = k >> 1; j >= 1; j >>= 1) {
            u64 pk = shflx64(key, j);
            bool wmax = (((lane & j) == 0) == ((lane & k) == 0));
            key = ((key > pk) == wmax) ? key : pk;
        }
    }
    return key;
}

// count of elements > x in descending-sorted LDS list D[0..N)
template<int N>
__device__ __forceinline__ int cnt_gt(const u64* D, u64 x) {
    int c = 0;
#pragma unroll
    for (int s = N; s >= 1; s >>= 1) {
        if (c + s <= N && D[c + s - 1] > x) c += s;
    }
    return c;
}

// ---- global -> LDS DMA, 16B/lane, wave-uniform LDS base ----
typedef const __attribute__((address_space(1))) unsigned int gas_u32;
typedef __attribute__((address_space(3))) unsigned int las_u32;
__device__ __forceinline__ void gll16(const float* g, float* l) {
    __builtin_amdgcn_global_load_lds((gas_u32*)g, (las_u32*)l, 16, 0, 0);
}

// stage 64B chunk c (cols 16c..16c+15) of R rows into buf[64][16] floats.
// instr k: 1KB = rows 16k..16k+15, lane L -> row 16k+(L>>2), dest slot L&3.
// source piece is XOR-swizzled so the LINEAR DMA dest holds swizzled layout:
// slot s of row r holds source piece s ^ ((r>>1)&3)  (involution).
template<int R>
__device__ __forceinline__ void stage_chunk(const float* __restrict__ Kb,
                                            int posme, int c, float* buf,
                                            int lane) {
#pragma unroll
    for (int k = 0; k < R / 16; ++k) {
        int r = 16 * k + (lane >> 2);
        int p = __shfl(posme, r, 64);            // row r's token position
        int piece = (lane & 3) ^ ((r >> 1) & 3); // source 16B piece
        const float* src = Kb + (size_t)p * Hn + c * 16 + piece * 4;
        gll16(src, buf + k * 256);               // 256 floats = 1KB/instr
    }
}

// sequential dot of chunk c: reads lane's row (source pieces j at LDS slot
// j^swz -> computed ADDRESSES, static registers), accumulates in source
// order 16c..16c+15. Chained over c=0..3 => exact element order 0..63,
// bit-identical to the round-9 dotq chain.
__device__ __forceinline__ float dot_chunk(const float* buf, const float* qs,
                                           int c, int lane, float acc) {
    const int swz = (lane >> 1) & 3;
    const float4* row = reinterpret_cast<const float4*>(buf + lane * 16);
    float4 v0 = row[0 ^ swz];
    float4 v1 = row[1 ^ swz];
    float4 v2 = row[2 ^ swz];
    float4 v3 = row[3 ^ swz];
    const float4* qv = reinterpret_cast<const float4*>(qs + c * 16);
    float4 q0 = qv[0], q1 = qv[1], q2 = qv[2], q3 = qv[3];
    acc = fmaf(q0.x, v0.x, acc); acc = fmaf(q0.y, v0.y, acc);
    acc = fmaf(q0.z, v0.z, acc); acc = fmaf(q0.w, v0.w, acc);
    acc = fmaf(q1.x, v1.x, acc); acc = fmaf(q1.y, v1.y, acc);
    acc = fmaf(q1.z, v1.z, acc); acc = fmaf(q1.w, v1.w, acc);
    acc = fmaf(q2.x, v2.x, acc); acc = fmaf(q2.y, v2.y, acc);
    acc = fmaf(q2.z, v2.z, acc); acc = fmaf(q2.w, v2.w, acc);
    acc = fmaf(q3.x, v3.x, acc); acc = fmaf(q3.y, v3.y, acc);
    acc = fmaf(q3.z, v3.z, acc); acc = fmaf(q3.w, v3.w, acc);
    return acc;
}

// full H=64 dot for R rows (lane <-> row), double-buffered 64B chunks with
// counted vmcnt so chunk c+1's DMA flies under chunk c's dot.
template<int R>
__device__ __forceinline__ float scored(const float* __restrict__ Kb,
                                        const float* qs, float* bufA,
                                        float* bufB, int posme, int lane) {
    stage_chunk<R>(Kb, posme, 0, bufA, lane);
    stage_chunk<R>(Kb, posme, 1, bufB, lane);
    float acc = 0.f;
    if constexpr (R == 64) { VMW(4); } else { VMW(2); }   // A(c0) landed
    acc = dot_chunk(bufA, qs, 0, lane, acc);
    WWAIT();                                              // A reads drained
    stage_chunk<R>(Kb, posme, 2, bufA, lane);
    if constexpr (R == 64) { VMW(4); } else { VMW(2); }   // B(c1) landed
    acc = dot_chunk(bufB, qs, 1, lane, acc);
    WWAIT();                                              // B reads drained
    stage_chunk<R>(Kb, posme, 3, bufB, lane);
    if constexpr (R == 64) { VMW(4); } else { VMW(2); }   // A(c2) landed
    acc = dot_chunk(bufA, qs, 2, lane, acc);
    VMW(0);                                               // B(c3) landed
    acc = dot_chunk(bufB, qs, 3, lane, acc);
    return acc;
}

__global__ void __launch_bounds__(256)
TreeAttention_70257075028607_kernel(
        const float* __restrict__ Q, const float* __restrict__ Kk,
        const float* __restrict__ V, float* __restrict__ O) {
    __shared__ __align__(16) float qsh[WV][Hn];
    __shared__ __align__(16) float kbsh[WV][2][1024];   // 2 x 4KB per wave
    __shared__ __align__(16) u64   Lsh[WV][64];
    __shared__ __align__(16) u64   Rsh[WV][64];
    __shared__ __align__(16) u64   Osh[WV][64];

    const int lane = threadIdx.x & 63;
    const int wv   = threadIdx.x >> 6;
    const int row  = blockIdx.x * WV + wv;      // n*T + t
    const int n    = row >> 11;
    const int t    = row & (Tn - 1);
    const float tp1 = (float)(t + 1);

    const float* qrow = Q + (size_t)row * Hn;
    const float* Kb   = Kk + (size_t)n * Tn * Hn;
    const float* Vb   = V  + (size_t)n * Tn * Hn;

    float* qs  = qsh[wv];
    float* kbA = kbsh[wv][0];
    float* kbB = kbsh[wv][1];
    u64* Lb = Lsh[wv];
    u64* Rb = Rsh[wv];
    u64* Ob = Osh[wv];

    qs[lane] = qrow[lane];
    WWAIT();

    int   myz  = 0;
    float mysc = NEGF;

    // ---- iter 1: w2=32, rows = cells z=0..31 (lane<->row), sort ----
    {
        const float ratio = tp1 * (1.f / 32.f);
        int posme = cpos(lane, ratio);           // valid for lane<32 (used)
        float s = scored<32>(Kb, qs, kbA, kbB, posme, lane);
        u64 key = (lane < 32) ? packkey(s, lane) : (u64)lane;
        key = bitonic_desc<32>(key, lane);
        if (lane < 32) { myz = dec_e(key); mysc = dec_score(key); }
    }

    // ---- iter 2: w2=64, 32 parents -> 64 children, keep all (sorted) ----
    {
        const float ratio = tp1 * (1.f / 64.f);
        int posme = cpos(2 * myz + 1, ratio);    // lane<32 rows
        float s1 = scored<32>(Kb, qs, kbA, kbB, posme, lane);
        u64 Lk = packkey(mysc, 2 * lane);        // parents sorted => L sorted
        u64 Rs = (lane < 32) ? packkey(s1, 2 * lane + 1) : (u64)lane;
        Rs = bitonic_desc<32>(Rs, lane);
        if (lane < 32) { Lb[lane] = Lk; Rb[lane] = Rs; }
        WWAIT();
        if (lane < 32) {
            int rL = lane + cnt_gt<32>(Rb, Lk);  // merge ranks: perm of 0..63
            int rR = lane + cnt_gt<32>(Lb, Rs);
            Ob[rL] = Lk;
            Ob[rR] = Rs;
        }
        WWAIT();
        u64 kk = Ob[lane];
        int e  = dec_e(kk);
        int pz = __shfl(myz, e >> 1, 64);
        myz  = 2 * pz + (e & 1);
        mysc = dec_score(kk);
    }

    // ---- iters 3..7: 64 parents -> 128 children, keep top-64 sorted ----
#pragma unroll
    for (int it = 0; it < 5; ++it) {
        const float ratio = tp1 * ldexpf(1.0f, -(7 + it));
        int posme = cpos(2 * myz + 1, ratio);    // this lane's right child
        float s1 = scored<64>(Kb, qs, kbA, kbB, posme, lane);
        u64 Lk = packkey(mysc, 2 * lane);        // sorted: parents in rank order
        u64 Rs = bitonic_desc<64>(packkey(s1, 2 * lane + 1), lane);
        Lb[lane] = Lk;
        Rb[lane] = Rs;
        WWAIT();
        int rL = lane + cnt_gt<64>(Rb, Lk);      // ranks: perm of 0..127
        int rR = lane + cnt_gt<64>(Lb, Rs);
        if (rL < 64) Ob[rL] = Lk;
        if (rR < 64) Ob[rR] = Rs;
        WWAIT();
        u64 kk = Ob[lane];
        int e  = dec_e(kk);
        int pz = __shfl(myz, e >> 1, 64);
        myz  = 2 * pz + (e & 1);
        mysc = dec_score(kk);
    }

    // ---- final: causal mask, softmax over 64, PV gather ----
    {
        int mypos  = cpos(myz, tp1 * (1.f / 2048.f));
        bool valid = ((float)mypos < tp1);
        float s = valid ? mysc * 0.125f : NEGF;  // / sqrt(64)

        float m = s;
#pragma unroll
        for (int off = 32; off >= 1; off >>= 1)
            m = fmaxf(m, __shfl_xor(m, off, 64));
        float p = expf(s - m);
        float sum = p;
#pragma unroll
        for (int off = 32; off >= 1; off >>= 1)
            sum += __shfl_xor(sum, off, 64);
        p = p / sum;
        if (!valid) p = 0.f;

        Ob[lane] = ((u64)(u32)mypos << 32) | __float_as_uint(p);
        WWAIT();

        float acc = 0.f;
#pragma unroll 8
        for (int jj = 0; jj < 64; ++jj) {
            u64 w = Ob[jj];
            acc = fmaf(__uint_as_float((u32)w),
                       Vb[(size_t)(w >> 32) * Hn + lane], acc);
        }
        O[(size_t)row * Hn + lane] = acc;
    }
}

extern "C" void kernel_launch(void* const* d_in, const int* in_sizes, int n_in,
                              void* d_out, int out_size, void* d_ws, size_t ws_size,
                              hipStream_t stream) {
    const float* Q = (const float*)d_in[0];
    const float* K = (const float*)d_in[1];
    const float* V = (const float*)d_in[2];
    float* O = (float*)d_out;

    const int rows = in_sizes[0] / Hn;   // N*T = 32768
    const int blocks = rows / WV;        // 8192
    TreeAttention_70257075028607_kernel<<<blocks, WV * 64, 0, stream>>>(Q, K, V, O);
}